// Round 1
// baseline (92.140 us; speedup 1.0000x reference)
//
#include <hip/hip_runtime.h>
#include <math.h>

// x: [32,3,512,512] f32.  Fused: Sobel -> mag -> 3x3 avgpool(stride1,pad1,/9)
// -> per-(b,c) sum & sumsq partials (double) per 64x64 tile.
// Grid: 96 (b,c) * 64 tiles = 6144 blocks, 256 threads.

#define SX_STRIDE 69   // 68 cols + 1 pad
#define SM_STRIDE 67   // 66 cols + 1 pad

__global__ __launch_bounds__(256) void sobel_pool_stats(
    const float* __restrict__ x, double* __restrict__ parts) {
  __shared__ float sx[68 * SX_STRIDE];
  __shared__ float sm[66 * SM_STRIDE];
  __shared__ double red[8];

  const int tid = threadIdx.x;
  const int bc = blockIdx.x >> 6;        // 0..95
  const int tile = blockIdx.x & 63;      // 0..63
  const int y0 = (tile >> 3) << 6;
  const int x0 = (tile & 7) << 6;
  const float* xb = x + (size_t)bc * (512 * 512);

  // ---- load x tile + halo(2): 68x68, zero-fill OOB ----
  for (int idx = tid; idx < 68 * 68; idx += 256) {
    int j = idx / 68;
    int i = idx - j * 68;
    int gy = y0 + j - 2;
    int gx = x0 + i - 2;
    float v = 0.f;
    if ((unsigned)gy < 512u && (unsigned)gx < 512u) v = xb[gy * 512 + gx];
    sx[j * SX_STRIDE + i] = v;
  }
  __syncthreads();

  // ---- mag tile + halo(1): 66x66; positions outside image -> 0 (pool pad) ----
  for (int idx = tid; idx < 66 * 66; idx += 256) {
    int j = idx / 66;
    int i = idx - j * 66;
    int gy = y0 + j - 1;
    int gx = x0 + i - 1;
    float m = 0.f;
    if ((unsigned)gy < 512u && (unsigned)gx < 512u) {
      const float* r0 = &sx[j * SX_STRIDE + i];
      float a = r0[0], b = r0[1], c = r0[2];
      float d = r0[SX_STRIDE], f = r0[SX_STRIDE + 2];
      float g = r0[2 * SX_STRIDE], h = r0[2 * SX_STRIDE + 1], k = r0[2 * SX_STRIDE + 2];
      // cross-correlation with sob_x = [[1,0,-1],[2,0,-2],[1,0,-1]]
      float gxv = (a - c) + 2.f * (d - f) + (g - k);
      // sob_y = sob_x^T = [[1,2,1],[0,0,0],[-1,-2,-1]]
      float gyv = (a + 2.f * b + c) - (g + 2.f * h + k);
      m = sqrtf(gxv * gxv + gyv * gyv + 1e-6f);
    }
    sm[j * SM_STRIDE + i] = m;
  }
  __syncthreads();

  // ---- 3x3 avg pool (sum/9), accumulate sum & sumsq in double ----
  const int tx = tid & 63;            // column 0..63
  const int r0 = (tid >> 6) * 16;     // 16 contiguous rows per thread
  double s = 0.0, ss = 0.0;
  const float* col = &sm[tx];
  float cs0, cs1;
  {
    const float* p = col + r0 * SM_STRIDE;
    cs0 = p[0] + p[1] + p[2];
    p += SM_STRIDE;
    cs1 = p[0] + p[1] + p[2];
  }
  for (int r = 0; r < 16; ++r) {
    const float* p = col + (r0 + r + 2) * SM_STRIDE;
    float cs2 = p[0] + p[1] + p[2];
    float pooled = (cs0 + cs1 + cs2) * (1.f / 9.f);
    s += (double)pooled;
    ss += (double)pooled * (double)pooled;
    cs0 = cs1;
    cs1 = cs2;
  }

  // ---- reduce across 64 lanes, then 4 waves ----
  for (int off = 32; off > 0; off >>= 1) {
    s += __shfl_down(s, off);
    ss += __shfl_down(ss, off);
  }
  const int wave = tid >> 6;
  if ((tid & 63) == 0) {
    red[wave * 2] = s;
    red[wave * 2 + 1] = ss;
  }
  __syncthreads();
  if (tid == 0) {
    double S = red[0] + red[2] + red[4] + red[6];
    double SS = red[1] + red[3] + red[5] + red[7];
    parts[(size_t)blockIdx.x * 2] = S;
    parts[(size_t)blockIdx.x * 2 + 1] = SS;
  }
}

// Reduce partials per (b,c), build feats [32,6] = [m0,s0,m1,s1,m2,s2], run MLP.
__global__ __launch_bounds__(256) void stats_mlp(
    const double* __restrict__ parts,
    const float* __restrict__ w1, const float* __restrict__ b1,
    const float* __restrict__ w2, const float* __restrict__ b2,
    float* __restrict__ out) {
  __shared__ float feats[32 * 6];
  __shared__ float hbuf[32 * 32];
  const int tid = threadIdx.x;

  if (tid < 96) {
    int b = tid / 3;
    int c = tid - b * 3;
    double s = 0.0, ss = 0.0;
    const double* p = parts + (size_t)tid * 128;  // 64 tiles * 2 doubles
    for (int t = 0; t < 64; ++t) {
      s += p[2 * t];
      ss += p[2 * t + 1];
    }
    const double N = 262144.0;
    double mean = s / N;
    double var = (ss - s * s / N) / (N - 1.0);
    if (var < 0.0) var = 0.0;
    feats[b * 6 + 2 * c] = (float)mean;
    feats[b * 6 + 2 * c + 1] = (float)sqrt(var);
  }
  __syncthreads();

  for (int idx = tid; idx < 32 * 32; idx += 256) {
    int i = idx >> 5, j = idx & 31;
    float acc = b1[j];
#pragma unroll
    for (int k = 0; k < 6; ++k) acc += feats[i * 6 + k] * w1[j * 6 + k];
    hbuf[idx] = acc > 0.f ? acc : 0.f;
  }
  __syncthreads();

  for (int idx = tid; idx < 2048; idx += 256) {
    int i = idx >> 6, o = idx & 63;
    float acc = b2[o];
#pragma unroll
    for (int j = 0; j < 32; ++j) acc += hbuf[i * 32 + j] * w2[o * 32 + j];
    out[idx] = acc;
  }
}

extern "C" void kernel_launch(void* const* d_in, const int* in_sizes, int n_in,
                              void* d_out, int out_size, void* d_ws, size_t ws_size,
                              hipStream_t stream) {
  const float* x = (const float*)d_in[0];
  const float* w1 = (const float*)d_in[1];
  const float* b1 = (const float*)d_in[2];
  const float* w2 = (const float*)d_in[3];
  const float* b2 = (const float*)d_in[4];
  float* out = (float*)d_out;
  double* parts = (double*)d_ws;  // 6144 * 2 doubles = 98304 B

  sobel_pool_stats<<<6144, 256, 0, stream>>>(x, parts);
  stats_mlp<<<1, 256, 0, stream>>>(parts, w1, b1, w2, b2, out);
}

// Round 2
// 50.055 us; speedup vs baseline: 1.8408x; 1.8408x over previous
//
#include <hip/hip_runtime.h>
#include <math.h>

// x: [32,3,512,512] f32.
// Fully register-resident row sweep: Sobel (separable) -> mag -> 3x3 avgpool
// (separable, zero-pad, /9) -> per-wave f32 partial sum/sumsq -> double partials.
// Each wave of 64 lanes owns a 64-column strip (60 output cols + 2 halo each
// side), sweeps 64 output rows. Horizontal neighbor access via __shfl (+/-1).
// No LDS, no __syncthreads in stage 1.
// Grid: (18, 96) blocks x 256 threads = 72 waves per (b,c): 9 strips x 8 chunks.

#define STRIPS 9
#define CHUNKS 8

__global__ __launch_bounds__(256) void sobel_pool_stats(
    const float* __restrict__ x, double* __restrict__ parts) {
  const int tid = threadIdx.x;
  const int lane = tid & 63;
  const int wib = tid >> 6;                    // wave in block 0..3
  const int bc = blockIdx.y;                   // 0..95
  const int wloc = blockIdx.x * 4 + wib;       // 0..71
  const int strip = wloc % STRIPS;
  const int chunk = wloc / STRIPS;

  const int c = strip * 60 + lane - 2;         // this lane's column, [-2,541]
  const int row0 = chunk * 64;                 // output rows row0..row0+63

  const float* __restrict__ xptr = x + (size_t)bc * (512 * 512);
  const bool colok = ((unsigned)c < 512u);
  const float colmask = colok ? 1.f : 0.f;
  const int cc = colok ? c : 0;                // clamped for safe addressing
  // lanes producing output: interior lanes with a real column
  const float outmask = (lane >= 2 && lane <= 61 && colok) ? (1.f / 9.f) : 0.f;

  // load x[r][c], 0 outside the image (rows clamped, masked; cols masked)
  auto loadrow = [&](int r) -> float {
    int rr = ((unsigned)r < 512u) ? r : 0;
    float rm = ((unsigned)r < 512u) ? colmask : 0.f;
    return xptr[rr * 512 + cc] * rm;
  };

  // Sobel magnitude for row mr from 3 x-rows (vertical combine in regs,
  // horizontal via shuffles). 0 for OOB rows/cols (pool zero-padding).
  auto magrow = [&](float xm, float x0, float xp, int mr) -> float {
    float a = (xm + xp) + 2.f * x0;            // vertical [1,2,1]  (for gx)
    float b = xm - xp;                         // vertical [1,0,-1] (for gy)
    float al = __shfl_up(a, 1);                // a(c-1)
    float ar = __shfl_down(a, 1);              // a(c+1)
    float bl = __shfl_up(b, 1);
    float br = __shfl_down(b, 1);
    float gx = al - ar;                        // horizontal [1,0,-1]
    float gy = (bl + br) + 2.f * b;            // horizontal [1,2,1]
    float m = sqrtf(gx * gx + gy * gy + 1e-6f);
    float rm = ((unsigned)mr < 512u) ? colmask : 0.f;
    return m * rm;
  };

  // warmup: mag rows row0-1 and row0
  float xm = loadrow(row0 - 2);
  float x0v = loadrow(row0 - 1);
  float xp = loadrow(row0);
  float mag_m = magrow(xm, x0v, xp, row0 - 1);
  float xq = loadrow(row0 + 1);
  float mag_c = magrow(x0v, xp, xq, row0);

  float xA = xp;   // x(r)
  float xB = xq;   // x(r+1)
  float s = 0.f, ss = 0.f;

#pragma unroll 4
  for (int i = 0; i < 64; ++i) {
    const int r = row0 + i;
    float xC = loadrow(r + 2);
    float mag_p = magrow(xA, xB, xC, r + 1);
    float cs = (mag_m + mag_p) + mag_c;        // vertical box [1,1,1]
    float csl = __shfl_up(cs, 1);
    float csr = __shfl_down(cs, 1);
    float pooled = ((csl + csr) + cs) * outmask;  // horizontal box, /9, masked
    s += pooled;
    ss += pooled * pooled;
    xA = xB; xB = xC; mag_m = mag_c; mag_c = mag_p;
  }

  // wave reduction in double (exact past this point)
  double ds = (double)s, dss = (double)ss;
  for (int off = 32; off > 0; off >>= 1) {
    ds += __shfl_down(ds, off);
    dss += __shfl_down(dss, off);
  }
  if (lane == 0) {
    size_t idx = ((size_t)bc * 72 + wloc) * 2;
    parts[idx] = ds;
    parts[idx + 1] = dss;
  }
}

// Reduce 72 wave-partials per (b,c), build feats [32,6]=[m0,s0,m1,s1,m2,s2],
// run the 6->32(relu)->64 MLP.
__global__ __launch_bounds__(256) void stats_mlp(
    const double* __restrict__ parts,
    const float* __restrict__ w1, const float* __restrict__ b1,
    const float* __restrict__ w2, const float* __restrict__ b2,
    float* __restrict__ out) {
  __shared__ float feats[32 * 6];
  __shared__ float hbuf[32 * 32];
  const int tid = threadIdx.x;

  if (tid < 96) {
    int b = tid / 3;
    int ch = tid - b * 3;
    double s = 0.0, ss = 0.0;
    const double* p = parts + (size_t)tid * 144;  // 72 waves * 2 doubles
    for (int t = 0; t < 72; ++t) {
      s += p[2 * t];
      ss += p[2 * t + 1];
    }
    const double N = 262144.0;
    double mean = s / N;
    double var = (ss - s * s / N) / (N - 1.0);
    if (var < 0.0) var = 0.0;
    feats[b * 6 + 2 * ch] = (float)mean;
    feats[b * 6 + 2 * ch + 1] = (float)sqrt(var);
  }
  __syncthreads();

  for (int idx = tid; idx < 32 * 32; idx += 256) {
    int i = idx >> 5, j = idx & 31;
    float acc = b1[j];
#pragma unroll
    for (int k = 0; k < 6; ++k) acc += feats[i * 6 + k] * w1[j * 6 + k];
    hbuf[idx] = acc > 0.f ? acc : 0.f;
  }
  __syncthreads();

  for (int idx = tid; idx < 2048; idx += 256) {
    int i = idx >> 6, o = idx & 63;
    float acc = b2[o];
#pragma unroll
    for (int j = 0; j < 32; ++j) acc += hbuf[i * 32 + j] * w2[o * 32 + j];
    out[idx] = acc;
  }
}

extern "C" void kernel_launch(void* const* d_in, const int* in_sizes, int n_in,
                              void* d_out, int out_size, void* d_ws, size_t ws_size,
                              hipStream_t stream) {
  const float* x = (const float*)d_in[0];
  const float* w1 = (const float*)d_in[1];
  const float* b1 = (const float*)d_in[2];
  const float* w2 = (const float*)d_in[3];
  const float* b2 = (const float*)d_in[4];
  float* out = (float*)d_out;
  double* parts = (double*)d_ws;  // 96*72*2 doubles = 110592 B

  dim3 grid(18, 96);
  sobel_pool_stats<<<grid, 256, 0, stream>>>(x, parts);
  stats_mlp<<<1, 256, 0, stream>>>(parts, w1, b1, w2, b2, out);
}